// Round 22
// baseline (188.186 us; speedup 1.0000x reference)
//
#include <hip/hip_runtime.h>
#include <hip/hip_bf16.h>

// Problem constants (fixed by the reference)
#define S_LEN 2048
#define BATCH 2
#define KDIM  2048
#define NH    32
#define NKV   8
#define HDIM  64

typedef short bf16s;
typedef short bf16x8 __attribute__((ext_vector_type(8)));
typedef short bf16x4 __attribute__((ext_vector_type(4)));
typedef float f32x4  __attribute__((ext_vector_type(4)));

#define KSCALE 0.1803368801111f   // 0.125 * log2(e): Q pre-scale -> log2-domain scores

// Session ledger (kept for future rounds):
// R3-R7: hand-written v_cvt_pk_bf16_f32 inline asm -> ~1e30 garbage. Use the
//        compiler's native cast.
// R8:    libm trig inside a GEMM epilogue -> OCML ABI caps VGPR at 36 -> spills.
// R13:   no-LDS-staging flash -> latency-bound (60 -> 187 us).
// R18:   KVBLK=128 -> VGPR 116 + 80KB LDS -> occupancy 16% -> regression.
// R19:   launch_bounds(256,4) -> VGPR squeezed to 64 < live state -> spills.
// R21:   Ps 8KB->4KB: LDS 40KB, occupancy unchanged (~26%) -> flash plateau is
//        grid-tail + barrier-drain structural, not LDS-capped.
__device__ __forceinline__ bf16s f2bf(float f) {
  __hip_bfloat16 h = __float2bfloat16(f);
  return *reinterpret_cast<bf16s*>(&h);
}
// 2^x via v_exp_f32 (no __exp2f fast intrinsic; glibc macro clash with __exp2f)
__device__ __forceinline__ float ex2(float x) { return __builtin_amdgcn_exp2f(x); }

// async global -> LDS, 16B per lane, LDS dest = wave-uniform base + lane*16
__device__ __forceinline__ void gload16(const void* g, void* l) {
  __builtin_amdgcn_global_load_lds(
      (const __attribute__((address_space(1))) char*)g,
      (__attribute__((address_space(3))) char*)l, 16, 0, 0);
}

// ---------------- fused fp32 -> bf16 convert + RoPE trig tables ----------------
__global__ void k_cvt_all(const float* __restrict__ s0, const float* __restrict__ s1,
                          const float* __restrict__ s2, const float* __restrict__ s3,
                          const float* __restrict__ s4, bf16s* __restrict__ dst,
                          float* __restrict__ qtab, float* __restrict__ ktab,
                          const int* __restrict__ pos) {
  const int t = blockIdx.x * blockDim.x + threadIdx.x;
  if (t < S_LEN * 32) {
    const int p = t >> 5, i = t & 31;
    const float inv = expf(-(float)(2 * i) * (1.0f / 64.0f) * 9.210340371976184f);
    const float fr = (float)p * inv;
    const float c = cosf(fr), s = sinf(fr);
    ktab[2 * t]     = c;
    ktab[2 * t + 1] = s;
    qtab[2 * t]     = c * KSCALE;
    qtab[2 * t + 1] = s * KSCALE;
  }
  const int NU = 2359296;                      // 18874368 / 8 vec8 units
  const int stride = gridDim.x * blockDim.x;
  for (int u = t; u < NU; u += stride) {
    const int e = u * 8;
    const float* src; int off;
    if (e < 8388608)       { src = s0; off = e; }            // x     (4096x2048)
    else if (e < 12582912) { src = s1; off = e - 8388608; }  // Wq    (2048x2048)
    else if (e < 13631488) { src = s2; off = e - 12582912; } // Wk    (512x2048)
    else if (e < 14680064) { src = s3; off = e - 13631488; } // Wv    (512x2048)
    else                   { src = s4; off = e - 14680064; } // Wo    (2048x2048)
    float4 a = *(const float4*)(src + off);
    float4 b = *(const float4*)(src + off + 4);
    bf16x8 o;
    o[0]=f2bf(a.x); o[1]=f2bf(a.y); o[2]=f2bf(a.z); o[3]=f2bf(a.w);
    o[4]=f2bf(b.x); o[5]=f2bf(b.y); o[6]=f2bf(b.z); o[7]=f2bf(b.w);
    *(bf16x8*)(dst + e) = o;
  }
}

// ---------------- Fused QKV GEMM + RoPE epilogue (BK=64, XOR-swizzled LDS) ----------------
__global__ __launch_bounds__(256, 2)
void k_gemm_qkv(const bf16s* __restrict__ A, const bf16s* __restrict__ Bw,
                const int* __restrict__ pos,
                const float* __restrict__ qtab, const float* __restrict__ ktab,
                bf16s* __restrict__ qb, bf16s* __restrict__ kb, bf16s* __restrict__ vtb) {
  const int K = KDIM;
  __shared__ bf16s As[128 * 64];   // 16 KB
  __shared__ bf16s Bs[128 * 64];   // 16 KB
  const int tid  = threadIdx.x;
  const int lane = tid & 63;
  const int w    = tid >> 6;
  const int wr   = w >> 1, wc = w & 1;
  const int l15  = lane & 15, lg = lane >> 4;
  // XCD-aware swizzle (T1): nwg=768, 768%8==0 -> bijective chunked remap
  const int h0 = blockIdx.y * 24 + blockIdx.x;
  const int sw = (h0 & 7) * 96 + (h0 >> 3);
  const int bx = sw % 24;
  const int by = sw / 24;

  f32x4 acc[4][4] = {};

  const int srow = (w << 3) + (lane >> 3);
  const int sc8  = ((lane & 7) ^ (lane >> 3)) << 3;
  const bf16s* gA = A  + (size_t)(by * 128 + srow) * K + sc8;
  const bf16s* gB = Bw + (size_t)(bx * 128 + srow) * K + sc8;
  bf16s* lA = &As[(w << 3) * 64];
  bf16s* lB = &Bs[(w << 3) * 64];

  const int nkt = K >> 6;
  for (int kt = 0; kt < nkt; ++kt) {
    __syncthreads();
    const int ko = kt << 6;
#pragma unroll
    for (int j = 0; j < 4; ++j) {
      gload16(gA + (size_t)(j * 32) * K + ko, lA + j * 2048);
      gload16(gB + (size_t)(j * 32) * K + ko, lB + j * 2048);
    }
    __syncthreads();

#pragma unroll
    for (int kk = 0; kk < 2; ++kk) {
      bf16x8 av[4], bv[4];
#pragma unroll
      for (int i = 0; i < 4; ++i) {
        const int ra = wr * 64 + i * 16 + l15;
        av[i] = *(const bf16x8*)&As[ra * 64 + ((kk * 32 + lg * 8) ^ ((ra & 7) << 3))];
        const int rb = wc * 64 + i * 16 + l15;
        bv[i] = *(const bf16x8*)&Bs[rb * 64 + ((kk * 32 + lg * 8) ^ ((rb & 7) << 3))];
      }
#pragma unroll
      for (int mi = 0; mi < 4; ++mi)
#pragma unroll
        for (int ni = 0; ni < 4; ++ni)
          acc[mi][ni] = __builtin_amdgcn_mfma_f32_16x16x32_bf16(av[mi], bv[ni], acc[mi][ni], 0, 0, 0);
    }
  }

#pragma unroll
  for (int mi = 0; mi < 4; ++mi) {
    const int m0 = by * 128 + wr * 64 + mi * 16 + 4 * lg;
#pragma unroll
    for (int ni = 0; ni < 4; ++ni) {
      const int n = bx * 128 + wc * 64 + ni * 16 + l15;
      if (bx < 16) {
        const int d = n & 63, i = d >> 1;
        const float sgn = (d & 1) ? 1.f : -1.f;
#pragma unroll
        for (int r = 0; r < 4; ++r) {
          const int m = m0 + r;
          const float val = acc[mi][ni][r];
          const float par = __shfl_xor(val, 1);
          const float2 cs = *(const float2*)&qtab[((size_t)pos[m] << 6) + (i << 1)];
          qb[(size_t)m * KDIM + n] = f2bf(val * cs.x + sgn * par * cs.y);
        }
      } else if (bx < 20) {
        const int col = n - 2048;
        const int d = col & 63, i = d >> 1;
        const float sgn = (d & 1) ? 1.f : -1.f;
#pragma unroll
        for (int r = 0; r < 4; ++r) {
          const int m = m0 + r;
          const float val = acc[mi][ni][r];
          const float par = __shfl_xor(val, 1);
          const float2 cs = *(const float2*)&ktab[((size_t)pos[m] << 6) + (i << 1)];
          kb[(size_t)m * 512 + col] = f2bf(val * cs.x + sgn * par * cs.y);
        }
      } else {
        const int col = n - 2560;
        const int kvh = col >> 6, d = col & 63;
        const int b = m0 >> 11, s = m0 & (S_LEN - 1);
        bf16x4 pk;
#pragma unroll
        for (int r = 0; r < 4; ++r) pk[r] = f2bf(acc[mi][ni][r]);
        *(bf16x4*)&vtb[((size_t)((b * NKV + kvh) * HDIM + d)) * S_LEN + s] = pk;
      }
    }
  }
}

// ---------------- O-proj GEMM (BK=64, XOR-swizzled LDS, fp32 out) ----------------
__global__ __launch_bounds__(256, 2)
void k_gemm_o(const bf16s* __restrict__ A, const bf16s* __restrict__ Bw,
              float* __restrict__ C, int N, int K) {
  __shared__ bf16s As[128 * 64];
  __shared__ bf16s Bs[128 * 64];
  const int tid  = threadIdx.x;
  const int lane = tid & 63;
  const int w    = tid >> 6;
  const int wr   = w >> 1, wc = w & 1;
  const int l15  = lane & 15, lg = lane >> 4;
  const int h0 = blockIdx.y * 16 + blockIdx.x;
  const int sw = (h0 & 7) * 64 + (h0 >> 3);
  const int bx = sw & 15;
  const int by = sw >> 4;

  f32x4 acc[4][4] = {};

  const int srow = (w << 3) + (lane >> 3);
  const int sc8  = ((lane & 7) ^ (lane >> 3)) << 3;
  const bf16s* gA = A  + (size_t)(by * 128 + srow) * K + sc8;
  const bf16s* gB = Bw + (size_t)(bx * 128 + srow) * K + sc8;
  bf16s* lA = &As[(w << 3) * 64];
  bf16s* lB = &Bs[(w << 3) * 64];

  const int nkt = K >> 6;
  for (int kt = 0; kt < nkt; ++kt) {
    __syncthreads();
    const int ko = kt << 6;
#pragma unroll
    for (int j = 0; j < 4; ++j) {
      gload16(gA + (size_t)(j * 32) * K + ko, lA + j * 2048);
      gload16(gB + (size_t)(j * 32) * K + ko, lB + j * 2048);
    }
    __syncthreads();

#pragma unroll
    for (int kk = 0; kk < 2; ++kk) {
      bf16x8 av[4], bv[4];
#pragma unroll
      for (int i = 0; i < 4; ++i) {
        const int ra = wr * 64 + i * 16 + l15;
        av[i] = *(const bf16x8*)&As[ra * 64 + ((kk * 32 + lg * 8) ^ ((ra & 7) << 3))];
        const int rb = wc * 64 + i * 16 + l15;
        bv[i] = *(const bf16x8*)&Bs[rb * 64 + ((kk * 32 + lg * 8) ^ ((rb & 7) << 3))];
      }
#pragma unroll
      for (int mi = 0; mi < 4; ++mi)
#pragma unroll
        for (int ni = 0; ni < 4; ++ni)
          acc[mi][ni] = __builtin_amdgcn_mfma_f32_16x16x32_bf16(av[mi], bv[ni], acc[mi][ni], 0, 0, 0);
    }
  }

#pragma unroll
  for (int mi = 0; mi < 4; ++mi) {
    const int m0 = by * 128 + wr * 64 + mi * 16 + 4 * lg;
#pragma unroll
    for (int ni = 0; ni < 4; ++ni) {
      const int n = bx * 128 + wc * 64 + ni * 16 + l15;
#pragma unroll
      for (int r = 0; r < 4; ++r)
        C[(size_t)(m0 + r) * N + n] = acc[mi][ni][r];
    }
  }
}

// ---------------- Flash attention (causal GQA), swapped-MFMA, log2 domain ----------------
// grid (B*H, 16 balanced qt); 4 waves x 32 q-rows; KV tiles of 64, dbuf via
// global_load_lds. R17/R20-proven configuration (73.2 us).
__global__ __launch_bounds__(256, 3)
void k_flash(const bf16s* __restrict__ q, const bf16s* __restrict__ k,
             const bf16s* __restrict__ vt, const int* __restrict__ amask,
             bf16s* __restrict__ out) {
  __shared__ bf16s Ks[2][64 * 64];   // [key][d], XOR-swizzled content, linear dest
  __shared__ bf16s Vs[2][64 * 64];   // [d][key] (V^T), XOR-swizzled
  __shared__ bf16s Ps[4][32 * 64];   // per-wave P[q'][key], XOR-swizzled

  const int tid = threadIdx.x, lane = tid & 63, w = tid >> 6;
  const int l15 = lane & 15, lg = lane >> 4;
  const int bh = blockIdx.x;
  // balanced qt permutation (bijective on 0..15; verified by enumeration)
  const int y = blockIdx.y, yq = y & 3, hi = (y >> 3) & 1;
  const int qt = (y & 4) ? (yq + (hi << 2)) : ((hi ? 11 : 15) - yq);
  const int b = bh >> 5, h = bh & 31, kvh = h >> 2;
  const int nt = 2 * qt + 2;

  // Q fragments (B-operand): lane holds Q[qrow = l15][d = s*32 + lg*8 + j]
  bf16x8 aq[2][2];
  const int qbase = qt * 128 + w * 32;
#pragma unroll
  for (int u = 0; u < 2; ++u) {
    const size_t qr = (size_t)(b * S_LEN + qbase + u * 16 + l15);
#pragma unroll
    for (int s = 0; s < 2; ++s)
      aq[u][s] = *(const bf16x8*)(q + qr * KDIM + h * HDIM + s * 32 + lg * 8);
  }

  const bf16s* kbase = k + (size_t)b * S_LEN * (NKV * HDIM) + kvh * HDIM;
  const bf16s* vbase = vt + ((size_t)(b * NKV + kvh) * HDIM) * S_LEN;

  // staging: LDS linear byte = w*2048 + j*1024 + lane*16 -> row, col16 = (lane&7)^(row&7)
  const int srow0 = w * 16 + (lane >> 3);
  const int scol0 = (lane & 7) ^ (srow0 & 7);
  const int srow1 = srow0 + 8;
  const int scol1 = (lane & 7) ^ (srow1 & 7);

  auto stage = [&](int kt, int bufi) {
    gload16(kbase + (size_t)(kt * 64 + srow0) * (NKV * HDIM) + scol0 * 8, &Ks[bufi][w * 1024]);
    gload16(kbase + (size_t)(kt * 64 + srow1) * (NKV * HDIM) + scol1 * 8, &Ks[bufi][w * 1024 + 512]);
    gload16(vbase + (size_t)srow0 * S_LEN + kt * 64 + scol0 * 8, &Vs[bufi][w * 1024]);
    gload16(vbase + (size_t)srow1 * S_LEN + kt * 64 + scol1 * 8, &Vs[bufi][w * 1024 + 512]);
  };

  float m_run[2] = {-1e30f, -1e30f}, l_run[2] = {0.f, 0.f};
  f32x4 ao[2][4] = {};

  stage(0, 0);
  __syncthreads();

  int buf = 0;
  for (int kt = 0; kt < nt; ++kt) {
    if (kt + 1 < nt) stage(kt + 1, buf ^ 1);

    const unsigned long long bm = __ballot(amask[b * S_LEN + kt * 64 + lane] != 0);
    const bool allok = (bm == ~0ull);
    const bool diag = (kt >= nt - 2);

    // QK^T (swapped): sc[u][c] = K-chunk(16key x 32d) x Q(16q x 32d); log2-domain
    f32x4 sc[2][4] = {};
    __builtin_amdgcn_s_setprio(1);
#pragma unroll
    for (int c = 0; c < 4; ++c) {
      const int row = c * 16 + l15;
      const bf16s* kp = &Ks[buf][row * 64];
      const int xw = (row & 7) << 3;
      bf16x8 kb0 = *(const bf16x8*)(kp + ((lg * 8) ^ xw));
      bf16x8 kb1 = *(const bf16x8*)(kp + ((32 + lg * 8) ^ xw));
      sc[0][c] = __builtin_amdgcn_mfma_f32_16x16x32_bf16(kb0, aq[0][0], sc[0][c], 0, 0, 0);
      sc[0][c] = __builtin_amdgcn_mfma_f32_16x16x32_bf16(kb1, aq[0][1], sc[0][c], 0, 0, 0);
      sc[1][c] = __builtin_amdgcn_mfma_f32_16x16x32_bf16(kb0, aq[1][0], sc[1][c], 0, 0, 0);
      sc[1][c] = __builtin_amdgcn_mfma_f32_16x16x32_bf16(kb1, aq[1][1], sc[1][c], 0, 0, 0);
    }
    __builtin_amdgcn_s_setprio(0);

    // online softmax (log2 domain); lane owns q = l15 (keys = c*16+lg*4+r)
#pragma unroll
    for (int u = 0; u < 2; ++u) {
      const int qg = qt * 128 + w * 32 + u * 16 + l15;
      float mt = -1e30f;
      if (diag || !allok) {
#pragma unroll
        for (int c = 0; c < 4; ++c)
#pragma unroll
          for (int r = 0; r < 4; ++r) {
            const int kg = kt * 64 + c * 16 + lg * 4 + r;
            float s = sc[u][c][r];
            if ((kg > qg) || (!allok && !((bm >> (kg & 63)) & 1))) s = -1e30f;
            sc[u][c][r] = s;
            mt = fmaxf(mt, s);
          }
      } else {
#pragma unroll
        for (int c = 0; c < 4; ++c)
#pragma unroll
          for (int r = 0; r < 4; ++r) mt = fmaxf(mt, sc[u][c][r]);
      }
      mt = fmaxf(mt, __shfl_xor(mt, 16));
      mt = fmaxf(mt, __shfl_xor(mt, 32));
      // exact defer-max (T13, THR=0): skipping is bit-identical when no row max grew
      if (!__all(mt <= m_run[u])) {
        const float mn = fmaxf(m_run[u], mt);
        const float al = ex2(m_run[u] - mn);
        m_run[u] = mn;
        l_run[u] *= al;
#pragma unroll
        for (int vc = 0; vc < 4; ++vc)
#pragma unroll
          for (int r = 0; r < 4; ++r) ao[u][vc][r] *= al;
      }
      const float mb = m_run[u];
      float ls = 0.f;
#pragma unroll
      for (int c = 0; c < 4; ++c) {
        bf16x4 pk;
#pragma unroll
        for (int r = 0; r < 4; ++r) {
          const float p = ex2(sc[u][c][r] - mb);
          ls += p;
          pk[r] = f2bf(p);
        }
        const int prow = u * 16 + l15;
        *(bf16x4*)&Ps[w][prow * 64 + ((c * 16 + lg * 4) ^ ((prow & 7) << 3))] = pk;
      }
      ls += __shfl_xor(ls, 16);
      ls += __shfl_xor(ls, 32);
      l_run[u] += ls;
    }

    // P fragments (B-operand): lane holds P[q = l15][key = s*32 + lg*8 + j]
    bf16x8 pa[2][2];
#pragma unroll
    for (int u = 0; u < 2; ++u) {
      const int prow = u * 16 + l15;
      const int px = (prow & 7) << 3;
#pragma unroll
      for (int s = 0; s < 2; ++s)
        pa[u][s] = *(const bf16x8*)&Ps[w][prow * 64 + ((s * 32 + lg * 8) ^ px)];
    }

    // PV (swapped): ao[u][vc] += V^T-chunk(16d x 32key) x P(16q x 32key)
    __builtin_amdgcn_s_setprio(1);
#pragma unroll
    for (int vc = 0; vc < 4; ++vc) {
      const int row = vc * 16 + l15;
      const bf16s* vp = &Vs[buf][row * 64];
      const int xw = (row & 7) << 3;
      bf16x8 vb0 = *(const bf16x8*)(vp + ((lg * 8) ^ xw));
      bf16x8 vb1 = *(const bf16x8*)(vp + ((32 + lg * 8) ^ xw));
      ao[0][vc] = __builtin_amdgcn_mfma_f32_16x16x32_bf16(vb0, pa[0][0], ao[0][vc], 0, 0, 0);
      ao[0][vc] = __builtin_amdgcn_mfma_f32_16x16x32_bf16(vb1, pa[0][1], ao[0][vc], 0, 0, 0);
      ao[1][vc] = __builtin_amdgcn_mfma_f32_16x16x32_bf16(vb0, pa[1][0], ao[1][vc], 0, 0, 0);
      ao[1][vc] = __builtin_amdgcn_mfma_f32_16x16x32_bf16(vb1, pa[1][1], ao[1][vc], 0, 0, 0);
    }
    __builtin_amdgcn_s_setprio(0);

    __syncthreads();
    buf ^= 1;
  }

  // epilogue: lane owns q = l15; d = vc*16 + lg*4 + r -> bf16x4 stores
#pragma unroll
  for (int u = 0; u < 2; ++u) {
    const float inv = 1.0f / l_run[u];
    const size_t m = (size_t)b * S_LEN + qt * 128 + w * 32 + u * 16 + l15;
#pragma unroll
    for (int vc = 0; vc < 4; ++vc) {
      bf16x4 ov;
#pragma unroll
      for (int r = 0; r < 4; ++r) ov[r] = f2bf(ao[u][vc][r] * inv);
      *(bf16x4*)&out[m * KDIM + h * HDIM + vc * 16 + lg * 4] = ov;
    }
  }
}

// ---------------- launch ----------------
extern "C" void kernel_launch(void* const* d_in, const int* in_sizes, int n_in,
                              void* d_out, int out_size, void* d_ws, size_t ws_size,
                              hipStream_t stream) {
  const float* x  = (const float*)d_in[0];
  const int* pos  = (const int*)d_in[1];
  const int* am   = (const int*)d_in[2];
  const float* Wq = (const float*)d_in[3];
  const float* Wk = (const float*)d_in[4];
  const float* Wv = (const float*)d_in[5];
  const float* Wo = (const float*)d_in[6];
  float* out = (float*)d_out;

  char* ws = (char*)d_ws;
  const int M = BATCH * S_LEN;                  // 4096
  bf16s* xb   = (bf16s*)(ws);                   // 4096x2048          (16.78 MB)
  bf16s* wqkv = (bf16s*)(ws + 16777216);        // 3072x2048          (12.58 MB)
  bf16s* wob  = (bf16s*)(ws + 29360128);        // 2048x2048          ( 8.39 MB)
  bf16s* qb   = (bf16s*)(ws + 37748736);        // 4096x2048 (scaled) (16.78 MB)
  bf16s* kb   = (bf16s*)(ws + 54525952);        // 4096x512           ( 4.19 MB)
  bf16s* vtb  = (bf16s*)(ws + 58720256);        // (2*8*64)x2048 V^T  ( 4.19 MB)
  bf16s* aob  = (bf16s*)(ws + 62914560);        // 4096x2048          (16.78 MB)
  float* qtab = (float*)(ws + 62914560);        // 512 KB  } overlap aob: written by
  float* ktab = (float*)(ws + 63438848);        // 512 KB  } k_cvt_all, read by k_gemm_qkv,
  // then the region is overwritten by k_flash's output (strict stream order).

  dim3 blk(256);

  k_cvt_all<<<dim3(2048), blk, 0, stream>>>(x, Wq, Wk, Wv, Wo, xb, qtab, ktab, pos);

  k_gemm_qkv<<<dim3(24, 32), blk, 0, stream>>>(xb, wqkv, pos, qtab, ktab, qb, kb, vtb);

  k_flash<<<dim3(BATCH * NH, S_LEN / 128), blk, 0, stream>>>(qb, kb, vtb, am, aob);

  k_gemm_o<<<dim3(16, 32), blk, 0, stream>>>(aob, wob, out, 2048, 2048);
}

// Round 23
// 187.364 us; speedup vs baseline: 1.0044x; 1.0044x over previous
//
#include <hip/hip_runtime.h>
#include <hip/hip_bf16.h>

// Problem constants (fixed by the reference)
#define S_LEN 2048
#define BATCH 2
#define KDIM  2048
#define NH    32
#define NKV   8
#define HDIM  64

typedef short bf16s;
typedef short bf16x8 __attribute__((ext_vector_type(8)));
typedef short bf16x4 __attribute__((ext_vector_type(4)));
typedef float f32x4  __attribute__((ext_vector_type(4)));

#define KSCALE 0.1803368801111f   // 0.125 * log2(e): Q pre-scale -> log2-domain scores

// Session ledger:
// R3-R7: hand-written v_cvt_pk_bf16_f32 inline asm -> ~1e30 garbage. Use the
//        compiler's native cast.
// R8:    libm trig inside a GEMM epilogue -> OCML ABI caps VGPR at 36 -> spills.
// R13:   no-LDS-staging flash -> latency-bound (60 -> 187 us).
// R18:   KVBLK=128 -> VGPR 116 + 80KB LDS -> occupancy 16% -> regression.
// R19:   launch_bounds(256,4) -> VGPR squeezed to 64 < live state -> spills.
// R21:   Ps 8KB->4KB: occupancy unchanged -> flash plateau is grid-tail +
//        barrier-drain structural, not LDS-capped.
// R20/R21/R22: converged at 187.6-188.2 us (flash ~73, qkv ~73, o-proj ~25,
//        cvt ~18). Final verified configuration.
__device__ __forceinline__ bf16s f2bf(float f) {
  __hip_bfloat16 h = __float2bfloat16(f);
  return *reinterpret_cast<bf16s*>(&h);
}
// 2^x via v_exp_f32 (no __exp2f fast intrinsic; glibc macro clash with __exp2f)
__device__ __forceinline__ float ex2(float x) { return __builtin_amdgcn_exp2f(x); }

// async global -> LDS, 16B per lane, LDS dest = wave-uniform base + lane*16
__device__ __forceinline__ void gload16(const void* g, void* l) {
  __builtin_amdgcn_global_load_lds(
      (const __attribute__((address_space(1))) char*)g,
      (__attribute__((address_space(3))) char*)l, 16, 0, 0);
}

// ---------------- fused fp32 -> bf16 convert + RoPE trig tables ----------------
__global__ void k_cvt_all(const float* __restrict__ s0, const float* __restrict__ s1,
                          const float* __restrict__ s2, const float* __restrict__ s3,
                          const float* __restrict__ s4, bf16s* __restrict__ dst,
                          float* __restrict__ qtab, float* __restrict__ ktab,
                          const int* __restrict__ pos) {
  const int t = blockIdx.x * blockDim.x + threadIdx.x;
  if (t < S_LEN * 32) {
    const int p = t >> 5, i = t & 31;
    const float inv = expf(-(float)(2 * i) * (1.0f / 64.0f) * 9.210340371976184f);
    const float fr = (float)p * inv;
    const float c = cosf(fr), s = sinf(fr);
    ktab[2 * t]     = c;
    ktab[2 * t + 1] = s;
    qtab[2 * t]     = c * KSCALE;
    qtab[2 * t + 1] = s * KSCALE;
  }
  const int NU = 2359296;                      // 18874368 / 8 vec8 units
  const int stride = gridDim.x * blockDim.x;
  for (int u = t; u < NU; u += stride) {
    const int e = u * 8;
    const float* src; int off;
    if (e < 8388608)       { src = s0; off = e; }            // x     (4096x2048)
    else if (e < 12582912) { src = s1; off = e - 8388608; }  // Wq    (2048x2048)
    else if (e < 13631488) { src = s2; off = e - 12582912; } // Wk    (512x2048)
    else if (e < 14680064) { src = s3; off = e - 13631488; } // Wv    (512x2048)
    else                   { src = s4; off = e - 14680064; } // Wo    (2048x2048)
    float4 a = *(const float4*)(src + off);
    float4 b = *(const float4*)(src + off + 4);
    bf16x8 o;
    o[0]=f2bf(a.x); o[1]=f2bf(a.y); o[2]=f2bf(a.z); o[3]=f2bf(a.w);
    o[4]=f2bf(b.x); o[5]=f2bf(b.y); o[6]=f2bf(b.z); o[7]=f2bf(b.w);
    *(bf16x8*)(dst + e) = o;
  }
}

// ---------------- Fused QKV GEMM + RoPE epilogue (BK=64, XOR-swizzled LDS) ----------------
__global__ __launch_bounds__(256, 2)
void k_gemm_qkv(const bf16s* __restrict__ A, const bf16s* __restrict__ Bw,
                const int* __restrict__ pos,
                const float* __restrict__ qtab, const float* __restrict__ ktab,
                bf16s* __restrict__ qb, bf16s* __restrict__ kb, bf16s* __restrict__ vtb) {
  const int K = KDIM;
  __shared__ bf16s As[128 * 64];   // 16 KB
  __shared__ bf16s Bs[128 * 64];   // 16 KB
  const int tid  = threadIdx.x;
  const int lane = tid & 63;
  const int w    = tid >> 6;
  const int wr   = w >> 1, wc = w & 1;
  const int l15  = lane & 15, lg = lane >> 4;
  // XCD-aware swizzle (T1): nwg=768, 768%8==0 -> bijective chunked remap
  const int h0 = blockIdx.y * 24 + blockIdx.x;
  const int sw = (h0 & 7) * 96 + (h0 >> 3);
  const int bx = sw % 24;
  const int by = sw / 24;

  f32x4 acc[4][4] = {};

  const int srow = (w << 3) + (lane >> 3);
  const int sc8  = ((lane & 7) ^ (lane >> 3)) << 3;
  const bf16s* gA = A  + (size_t)(by * 128 + srow) * K + sc8;
  const bf16s* gB = Bw + (size_t)(bx * 128 + srow) * K + sc8;
  bf16s* lA = &As[(w << 3) * 64];
  bf16s* lB = &Bs[(w << 3) * 64];

  const int nkt = K >> 6;
  for (int kt = 0; kt < nkt; ++kt) {
    __syncthreads();
    const int ko = kt << 6;
#pragma unroll
    for (int j = 0; j < 4; ++j) {
      gload16(gA + (size_t)(j * 32) * K + ko, lA + j * 2048);
      gload16(gB + (size_t)(j * 32) * K + ko, lB + j * 2048);
    }
    __syncthreads();

#pragma unroll
    for (int kk = 0; kk < 2; ++kk) {
      bf16x8 av[4], bv[4];
#pragma unroll
      for (int i = 0; i < 4; ++i) {
        const int ra = wr * 64 + i * 16 + l15;
        av[i] = *(const bf16x8*)&As[ra * 64 + ((kk * 32 + lg * 8) ^ ((ra & 7) << 3))];
        const int rb = wc * 64 + i * 16 + l15;
        bv[i] = *(const bf16x8*)&Bs[rb * 64 + ((kk * 32 + lg * 8) ^ ((rb & 7) << 3))];
      }
#pragma unroll
      for (int mi = 0; mi < 4; ++mi)
#pragma unroll
        for (int ni = 0; ni < 4; ++ni)
          acc[mi][ni] = __builtin_amdgcn_mfma_f32_16x16x32_bf16(av[mi], bv[ni], acc[mi][ni], 0, 0, 0);
    }
  }

#pragma unroll
  for (int mi = 0; mi < 4; ++mi) {
    const int m0 = by * 128 + wr * 64 + mi * 16 + 4 * lg;
#pragma unroll
    for (int ni = 0; ni < 4; ++ni) {
      const int n = bx * 128 + wc * 64 + ni * 16 + l15;
      if (bx < 16) {
        const int d = n & 63, i = d >> 1;
        const float sgn = (d & 1) ? 1.f : -1.f;
#pragma unroll
        for (int r = 0; r < 4; ++r) {
          const int m = m0 + r;
          const float val = acc[mi][ni][r];
          const float par = __shfl_xor(val, 1);
          const float2 cs = *(const float2*)&qtab[((size_t)pos[m] << 6) + (i << 1)];
          qb[(size_t)m * KDIM + n] = f2bf(val * cs.x + sgn * par * cs.y);
        }
      } else if (bx < 20) {
        const int col = n - 2048;
        const int d = col & 63, i = d >> 1;
        const float sgn = (d & 1) ? 1.f : -1.f;
#pragma unroll
        for (int r = 0; r < 4; ++r) {
          const int m = m0 + r;
          const float val = acc[mi][ni][r];
          const float par = __shfl_xor(val, 1);
          const float2 cs = *(const float2*)&ktab[((size_t)pos[m] << 6) + (i << 1)];
          kb[(size_t)m * 512 + col] = f2bf(val * cs.x + sgn * par * cs.y);
        }
      } else {
        const int col = n - 2560;
        const int kvh = col >> 6, d = col & 63;
        const int b = m0 >> 11, s = m0 & (S_LEN - 1);
        bf16x4 pk;
#pragma unroll
        for (int r = 0; r < 4; ++r) pk[r] = f2bf(acc[mi][ni][r]);
        *(bf16x4*)&vtb[((size_t)((b * NKV + kvh) * HDIM + d)) * S_LEN + s] = pk;
      }
    }
  }
}

// ---------------- O-proj GEMM (BK=64, XOR-swizzled LDS, fp32 out) ----------------
__global__ __launch_bounds__(256, 2)
void k_gemm_o(const bf16s* __restrict__ A, const bf16s* __restrict__ Bw,
              float* __restrict__ C, int N, int K) {
  __shared__ bf16s As[128 * 64];
  __shared__ bf16s Bs[128 * 64];
  const int tid  = threadIdx.x;
  const int lane = tid & 63;
  const int w    = tid >> 6;
  const int wr   = w >> 1, wc = w & 1;
  const int l15  = lane & 15, lg = lane >> 4;
  const int h0 = blockIdx.y * 16 + blockIdx.x;
  const int sw = (h0 & 7) * 64 + (h0 >> 3);
  const int bx = sw & 15;
  const int by = sw >> 4;

  f32x4 acc[4][4] = {};

  const int srow = (w << 3) + (lane >> 3);
  const int sc8  = ((lane & 7) ^ (lane >> 3)) << 3;
  const bf16s* gA = A  + (size_t)(by * 128 + srow) * K + sc8;
  const bf16s* gB = Bw + (size_t)(bx * 128 + srow) * K + sc8;
  bf16s* lA = &As[(w << 3) * 64];
  bf16s* lB = &Bs[(w << 3) * 64];

  const int nkt = K >> 6;
  for (int kt = 0; kt < nkt; ++kt) {
    __syncthreads();
    const int ko = kt << 6;
#pragma unroll
    for (int j = 0; j < 4; ++j) {
      gload16(gA + (size_t)(j * 32) * K + ko, lA + j * 2048);
      gload16(gB + (size_t)(j * 32) * K + ko, lB + j * 2048);
    }
    __syncthreads();

#pragma unroll
    for (int kk = 0; kk < 2; ++kk) {
      bf16x8 av[4], bv[4];
#pragma unroll
      for (int i = 0; i < 4; ++i) {
        const int ra = wr * 64 + i * 16 + l15;
        av[i] = *(const bf16x8*)&As[ra * 64 + ((kk * 32 + lg * 8) ^ ((ra & 7) << 3))];
        const int rb = wc * 64 + i * 16 + l15;
        bv[i] = *(const bf16x8*)&Bs[rb * 64 + ((kk * 32 + lg * 8) ^ ((rb & 7) << 3))];
      }
#pragma unroll
      for (int mi = 0; mi < 4; ++mi)
#pragma unroll
        for (int ni = 0; ni < 4; ++ni)
          acc[mi][ni] = __builtin_amdgcn_mfma_f32_16x16x32_bf16(av[mi], bv[ni], acc[mi][ni], 0, 0, 0);
    }
  }

#pragma unroll
  for (int mi = 0; mi < 4; ++mi) {
    const int m0 = by * 128 + wr * 64 + mi * 16 + 4 * lg;
#pragma unroll
    for (int ni = 0; ni < 4; ++ni) {
      const int n = bx * 128 + wc * 64 + ni * 16 + l15;
#pragma unroll
      for (int r = 0; r < 4; ++r)
        C[(size_t)(m0 + r) * N + n] = acc[mi][ni][r];
    }
  }
}

// ---------------- Flash attention (causal GQA), swapped-MFMA, log2 domain ----------------
// grid (B*H, 16 balanced qt); 4 waves x 32 q-rows; KV tiles of 64, dbuf via
// global_load_lds. R17/R20-proven configuration (73.2 us).
__global__ __launch_bounds__(256, 3)
void k_flash(const bf16s* __restrict__ q, const bf16s* __restrict__ k,
             const bf16s* __restrict__ vt, const int* __restrict__ amask,
             bf16s* __restrict__ out) {
  __shared__ bf16s Ks[2][64 * 64];   // [key][d], XOR-swizzled content, linear dest
  __shared__ bf16s Vs[2][64 * 64];   // [d][key] (V^T), XOR-swizzled
  __shared__ bf16s Ps[4][32 * 64];   // per-wave P[q'][key], XOR-swizzled

  const int tid = threadIdx.x, lane = tid & 63, w = tid >> 6;
  const int l15 = lane & 15, lg = lane >> 4;
  const int bh = blockIdx.x;
  // balanced qt permutation (bijective on 0..15; verified by enumeration)
  const int y = blockIdx.y, yq = y & 3, hi = (y >> 3) & 1;
  const int qt = (y & 4) ? (yq + (hi << 2)) : ((hi ? 11 : 15) - yq);
  const int b = bh >> 5, h = bh & 31, kvh = h >> 2;
  const int nt = 2 * qt + 2;

  // Q fragments (B-operand): lane holds Q[qrow = l15][d = s*32 + lg*8 + j]
  bf16x8 aq[2][2];
  const int qbase = qt * 128 + w * 32;
#pragma unroll
  for (int u = 0; u < 2; ++u) {
    const size_t qr = (size_t)(b * S_LEN + qbase + u * 16 + l15);
#pragma unroll
    for (int s = 0; s < 2; ++s)
      aq[u][s] = *(const bf16x8*)(q + qr * KDIM + h * HDIM + s * 32 + lg * 8);
  }

  const bf16s* kbase = k + (size_t)b * S_LEN * (NKV * HDIM) + kvh * HDIM;
  const bf16s* vbase = vt + ((size_t)(b * NKV + kvh) * HDIM) * S_LEN;

  // staging: LDS linear byte = w*2048 + j*1024 + lane*16 -> row, col16 = (lane&7)^(row&7)
  const int srow0 = w * 16 + (lane >> 3);
  const int scol0 = (lane & 7) ^ (srow0 & 7);
  const int srow1 = srow0 + 8;
  const int scol1 = (lane & 7) ^ (srow1 & 7);

  auto stage = [&](int kt, int bufi) {
    gload16(kbase + (size_t)(kt * 64 + srow0) * (NKV * HDIM) + scol0 * 8, &Ks[bufi][w * 1024]);
    gload16(kbase + (size_t)(kt * 64 + srow1) * (NKV * HDIM) + scol1 * 8, &Ks[bufi][w * 1024 + 512]);
    gload16(vbase + (size_t)srow0 * S_LEN + kt * 64 + scol0 * 8, &Vs[bufi][w * 1024]);
    gload16(vbase + (size_t)srow1 * S_LEN + kt * 64 + scol1 * 8, &Vs[bufi][w * 1024 + 512]);
  };

  float m_run[2] = {-1e30f, -1e30f}, l_run[2] = {0.f, 0.f};
  f32x4 ao[2][4] = {};

  stage(0, 0);
  __syncthreads();

  int buf = 0;
  for (int kt = 0; kt < nt; ++kt) {
    if (kt + 1 < nt) stage(kt + 1, buf ^ 1);

    const unsigned long long bm = __ballot(amask[b * S_LEN + kt * 64 + lane] != 0);
    const bool allok = (bm == ~0ull);
    const bool diag = (kt >= nt - 2);

    // QK^T (swapped): sc[u][c] = K-chunk(16key x 32d) x Q(16q x 32d); log2-domain
    f32x4 sc[2][4] = {};
    __builtin_amdgcn_s_setprio(1);
#pragma unroll
    for (int c = 0; c < 4; ++c) {
      const int row = c * 16 + l15;
      const bf16s* kp = &Ks[buf][row * 64];
      const int xw = (row & 7) << 3;
      bf16x8 kb0 = *(const bf16x8*)(kp + ((lg * 8) ^ xw));
      bf16x8 kb1 = *(const bf16x8*)(kp + ((32 + lg * 8) ^ xw));
      sc[0][c] = __builtin_amdgcn_mfma_f32_16x16x32_bf16(kb0, aq[0][0], sc[0][c], 0, 0, 0);
      sc[0][c] = __builtin_amdgcn_mfma_f32_16x16x32_bf16(kb1, aq[0][1], sc[0][c], 0, 0, 0);
      sc[1][c] = __builtin_amdgcn_mfma_f32_16x16x32_bf16(kb0, aq[1][0], sc[1][c], 0, 0, 0);
      sc[1][c] = __builtin_amdgcn_mfma_f32_16x16x32_bf16(kb1, aq[1][1], sc[1][c], 0, 0, 0);
    }
    __builtin_amdgcn_s_setprio(0);

    // online softmax (log2 domain); lane owns q = l15 (keys = c*16+lg*4+r)
#pragma unroll
    for (int u = 0; u < 2; ++u) {
      const int qg = qt * 128 + w * 32 + u * 16 + l15;
      float mt = -1e30f;
      if (diag || !allok) {
#pragma unroll
        for (int c = 0; c < 4; ++c)
#pragma unroll
          for (int r = 0; r < 4; ++r) {
            const int kg = kt * 64 + c * 16 + lg * 4 + r;
            float s = sc[u][c][r];
            if ((kg > qg) || (!allok && !((bm >> (kg & 63)) & 1))) s = -1e30f;
            sc[u][c][r] = s;
            mt = fmaxf(mt, s);
          }
      } else {
#pragma unroll
        for (int c = 0; c < 4; ++c)
#pragma unroll
          for (int r = 0; r < 4; ++r) mt = fmaxf(mt, sc[u][c][r]);
      }
      mt = fmaxf(mt, __shfl_xor(mt, 16));
      mt = fmaxf(mt, __shfl_xor(mt, 32));
      // exact defer-max (T13, THR=0): skipping is bit-identical when no row max grew
      if (!__all(mt <= m_run[u])) {
        const float mn = fmaxf(m_run[u], mt);
        const float al = ex2(m_run[u] - mn);
        m_run[u] = mn;
        l_run[u] *= al;
#pragma unroll
        for (int vc = 0; vc < 4; ++vc)
#pragma unroll
          for (int r = 0; r < 4; ++r) ao[u][vc][r] *= al;
      }
      const float mb = m_run[u];
      float ls = 0.f;
#pragma unroll
      for (int c = 0; c < 4; ++c) {
        bf16x4 pk;
#pragma unroll
        for (int r = 0; r < 4; ++r) {
          const float p = ex2(sc[u][c][r] - mb);
          ls += p;
          pk[r] = f2bf(p);
        }
        const int prow = u * 16 + l15;
        *(bf16x4*)&Ps[w][prow * 64 + ((c * 16 + lg * 4) ^ ((prow & 7) << 3))] = pk;
      }
      ls += __shfl_xor(ls, 16);
      ls += __shfl_xor(ls, 32);
      l_run[u] += ls;
    }

    // P fragments (B-operand): lane holds P[q = l15][key = s*32 + lg*8 + j]
    bf16x8 pa[2][2];
#pragma unroll
    for (int u = 0; u < 2; ++u) {
      const int prow = u * 16 + l15;
      const int px = (prow & 7) << 3;
#pragma unroll
      for (int s = 0; s < 2; ++s)
        pa[u][s] = *(const bf16x8*)&Ps[w][prow * 64 + ((s * 32 + lg * 8) ^ px)];
    }

    // PV (swapped): ao[u][vc] += V^T-chunk(16d x 32key) x P(16q x 32key)
    __builtin_amdgcn_s_setprio(1);
#pragma unroll
    for (int vc = 0; vc < 4; ++vc) {
      const int row = vc * 16 + l15;
      const bf16s* vp = &Vs[buf][row * 64];
      const int xw = (row & 7) << 3;
      bf16x8 vb0 = *(const bf16x8*)(vp + ((lg * 8) ^ xw));
      bf16x8 vb1 = *(const bf16x8*)(vp + ((32 + lg * 8) ^ xw));
      ao[0][vc] = __builtin_amdgcn_mfma_f32_16x16x32_bf16(vb0, pa[0][0], ao[0][vc], 0, 0, 0);
      ao[0][vc] = __builtin_amdgcn_mfma_f32_16x16x32_bf16(vb1, pa[0][1], ao[0][vc], 0, 0, 0);
      ao[1][vc] = __builtin_amdgcn_mfma_f32_16x16x32_bf16(vb0, pa[1][0], ao[1][vc], 0, 0, 0);
      ao[1][vc] = __builtin_amdgcn_mfma_f32_16x16x32_bf16(vb1, pa[1][1], ao[1][vc], 0, 0, 0);
    }
    __builtin_amdgcn_s_setprio(0);

    __syncthreads();
    buf ^= 1;
  }

  // epilogue: lane owns q = l15; d = vc*16 + lg*4 + r -> bf16x4 stores
#pragma unroll
  for (int u = 0; u < 2; ++u) {
    const float inv = 1.0f / l_run[u];
    const size_t m = (size_t)b * S_LEN + qt * 128 + w * 32 + u * 16 + l15;
#pragma unroll
    for (int vc = 0; vc < 4; ++vc) {
      bf16x4 ov;
#pragma unroll
      for (int r = 0; r < 4; ++r) ov[r] = f2bf(ao[u][vc][r] * inv);
      *(bf16x4*)&out[m * KDIM + h * HDIM + vc * 16 + lg * 4] = ov;
    }
  }
}

// ---------------- launch ----------------
extern "C" void kernel_launch(void* const* d_in, const int* in_sizes, int n_in,
                              void* d_out, int out_size, void* d_ws, size_t ws_size,
                              hipStream_t stream) {
  const float* x  = (const float*)d_in[0];
  const int* pos  = (const int*)d_in[1];
  const int* am   = (const int*)d_in[2];
  const float* Wq = (const float*)d_in[3];
  const float* Wk = (const float*)d_in[4];
  const float* Wv = (const float*)d_in[5];
  const float* Wo = (const float*)d_in[6];
  float* out = (float*)d_out;

  char* ws = (char*)d_ws;
  const int M = BATCH * S_LEN;                  // 4096
  bf16s* xb   = (bf16s*)(ws);                   // 4096x2048          (16.78 MB)
  bf16s* wqkv = (bf16s*)(ws + 16777216);        // 3072x2048          (12.58 MB)
  bf16s* wob  = (bf16s*)(ws + 29360128);        // 2048x2048          ( 8.39 MB)
  bf16s* qb   = (bf16s*)(ws + 37748736);        // 4096x2048 (scaled) (16.78 MB)
  bf16s* kb   = (bf16s*)(ws + 54525952);        // 4096x512           ( 4.19 MB)
  bf16s* vtb  = (bf16s*)(ws + 58720256);        // (2*8*64)x2048 V^T  ( 4.19 MB)
  bf16s* aob  = (bf16s*)(ws + 62914560);        // 4096x2048          (16.78 MB)
  float* qtab = (float*)(ws + 62914560);        // 512 KB  } overlap aob: written by
  float* ktab = (float*)(ws + 63438848);        // 512 KB  } k_cvt_all, read by k_gemm_qkv,
  // then the region is overwritten by k_flash's output (strict stream order).

  dim3 blk(256);

  k_cvt_all<<<dim3(2048), blk, 0, stream>>>(x, Wq, Wk, Wv, Wo, xb, qtab, ktab, pos);

  k_gemm_qkv<<<dim3(24, 32), blk, 0, stream>>>(xb, wqkv, pos, qtab, ktab, qb, kb, vtb);

  k_flash<<<dim3(BATCH * NH, S_LEN / 128), blk, 0, stream>>>(qb, kb, vtb, am, aob);

  k_gemm_o<<<dim3(16, 32), blk, 0, stream>>>(aob, wob, out, 2048, 2048);
}